// Round 20
// baseline (459.136 us; speedup 1.0000x reference)
//
#include <hip/hip_runtime.h>

#define NN 64
#define IN_DIM 34
#define SUN 70
#define NL 3
#define NH 5

typedef __attribute__((ext_vector_type(8))) short short8;
typedef __attribute__((ext_vector_type(4))) short short4v;
typedef __attribute__((ext_vector_type(4))) float f32x4;
#define MFMA16 __builtin_amdgcn_mfma_f32_16x16x32_bf16

__device__ __forceinline__ float sigm(float x){ return 1.0f/(1.0f+__expf(-x)); }
__device__ __forceinline__ float ftanh(float x){
  x = fminf(fmaxf(x, -15.0f), 15.0f);
  float e = __expf(2.0f*x);
  return (e-1.0f)/(e+1.0f);
}
__device__ __forceinline__ ushort f2bf(float f){
  union { float f; unsigned u; } v; v.f = f;
  unsigned r = v.u + 0x7fff + ((v.u >> 16) & 1);   // RNE
  return (ushort)(r >> 16);
}
__device__ __forceinline__ float bf2f(ushort h){
  union { unsigned u; float f; } v; v.u = ((unsigned)h) << 16;
  return v.f;
}

// ws ushort offsets (weights single-bf16; adj hi/lo)
#define O_WPH 0
#define O_WSH 4096
#define O_WNH 16384
#define O_A1H 28672
#define O_ADJH 38912
#define O_ADJL 43008

// fragment-order permutation within a plane (coalesced GBF reads)
__device__ __forceinline__ int fragoff(int i){
  int e = i>>6, k = i&63;
  int t = e>>4, cc = e&15, kt = (k>>5)&1, hk = (k>>3)&3, j = k&7;
  return (((t*2+kt)*64) + (hk*16+cc))*8 + j;
}

// LDS frag read: storage [entity][k] swizzled; entity = 16t+c, k = hk*8 + kt*32
#define LDF(plane, t, kt) \
  (*(const short8*)&(plane)[(16*(t)+c)*64 + (((hk*8)+(kt)*32) ^ (((16*(t)+c)&7)<<3))])
// global wb frag read (fragment-ordered, fully coalesced)
#define GBF(base, t, kt) \
  (*(const short8*)&(base)[(((t)*2+(kt))*64 + lane)*8])
// C-frag LDS offset for (mt,nt)
#define CFO(mt, nt) ((16*(nt)+c)*64 + (((16*(mt)+hk*4)) ^ (((16*(nt)+c)&7)<<3)))

// Setup: dense normalized adjacency (hi/lo) + weights single-bf16, frag-ordered.
__global__ void setup_k(const int* __restrict__ ei, int E,
                        const float* __restrict__ Wp, const float* __restrict__ Wself,
                        const float* __restrict__ Wneigh, const float* __restrict__ a1W,
                        ushort* __restrict__ wb){
  __shared__ float A[64*64];
  __shared__ float dv[64];
  int tid = threadIdx.x;
  for (int i=tid;i<4096;i+=256) A[i]=0.0f;
  __syncthreads();
  if (tid==0){
    for (int e=0;e<E;++e) A[ei[E+e]*64 + ei[e]] += 1.0f;
  }
  __syncthreads();
  if (tid<64){
    float s=0.0f;
    for (int k=0;k<64;++k) s += A[tid*64+k];
    dv[tid] = 1.0f/fmaxf(s,1.0f);
  }
  __syncthreads();
  for (int i=tid;i<4096;i+=256){
    int d=i>>6;
    float v = A[i]*dv[d];
    ushort h=f2bf(v);
    int fo = fragoff(i);
    wb[O_ADJH+fo]=h; wb[O_ADJL+fo]=f2bf(v-bf2f(h));
  }
  for (int i = tid; i < 4096; i += 256){
    int n = i>>6, k = i&63;
    float w = (k < IN_DIM) ? Wp[k*64 + n] : 0.0f;
    wb[O_WPH+fragoff(i)] = f2bf(w);
  }
  for (int i = tid; i < 3*4096; i += 256){
    int L = i>>12, r = i&4095, n = r>>6, k = r&63;
    int fo = L*4096 + fragoff(r);
    wb[O_WSH+fo] = f2bf(Wself[L*4096 + k*64 + n]);
    wb[O_WNH+fo] = f2bf(Wneigh[L*4096 + k*64 + n]);
  }
  for (int i = tid; i < 5*2048; i += 256){
    int hd = i>>11, r = i&2047, cc = r>>6, k = r&63;
    wb[O_A1H + hd*2048 + fragoff(r)] = f2bf(a1W[hd*2048 + k*32 + cc]);
  }
}

__global__ __launch_bounds__(256, 3) void gnn_fused(
    const float* __restrict__ nf, const float* __restrict__ sun,
    const int* __restrict__ masks,
    const float* __restrict__ bp, const float* __restrict__ bconv,
    const float* __restrict__ lng, const float* __restrict__ lnb,
    const float* __restrict__ Wcod, const float* __restrict__ bcod,
    const float* __restrict__ a1b, const float* __restrict__ a2W,
    const float* __restrict__ a2b,
    const float* __restrict__ oW, const float* __restrict__ ob,
    const float* __restrict__ fW1, const float* __restrict__ fb1,
    const float* __restrict__ fW2, const float* __restrict__ fb2,
    const ushort* __restrict__ wb, int B,
    float* __restrict__ out)
{
  __shared__ ushort s_x[4][4096];    // per-wave x: bf16 hi only, swizzled [node][feat]
  __shared__ ushort s_slab[4][1024]; // per-wave yT slab, single bf16

  const int tid  = threadIdx.x;
  const int lane = tid & 63;
  const int wv   = __builtin_amdgcn_readfirstlane(tid >> 6);
  const int c    = lane & 15;
  const int hk   = lane >> 4;
  const long e   = (long)blockIdx.x*4 + wv;
  if (e >= B) return;

  ushort* xp = s_x[wv];
  ushort* sl = s_slab[wv];
  float*  oute = out + e*69;

  // ---- stage nf into xp (hi only), coalesced float2 loads ----
  {
    const float* nfe = nf + e*(long)(NN*IN_DIM);
    for (int p = lane; p < 1088; p += 64){           // 17 iters, fully coalesced
      int n = p/17, k = 2*(p - n*17);
      float2 v = *(const float2*)&nfe[n*IN_DIM + k];
      int off = n*64 + (k ^ ((n&7)<<3));
      *(unsigned*)&xp[off] = (unsigned)f2bf(v.x) | ((unsigned)f2bf(v.y)<<16);
    }
    int n = lane, key = (n&7)<<3;
    int off34 = n*64 + (34 ^ key);
    *(unsigned*)&xp[off34] = 0;
    #pragma unroll
    for (int k4 = 9; k4 < 16; ++k4){
      int off = n*64 + ((k4*4) ^ key);
      *(short4v*)&xp[off] = (short4v){0,0,0,0};
    }
    asm volatile("s_waitcnt lgkmcnt(0)" ::: "memory");
  }

  // ---- proj^T = Wp^T(A,hi) @ nf^T(B,hi): relu -> LDS (hi) ----
  {
    f32x4 acc[4][4];
    #pragma unroll
    for (int mt=0;mt<4;++mt){
      f32x4 b4 = *(const f32x4*)&bp[16*mt + hk*4];
      #pragma unroll
      for (int nt=0;nt<4;++nt) acc[mt][nt] = b4;
    }
    #pragma unroll
    for (int kt=0; kt<2; ++kt){
      short8 bH[4];
      #pragma unroll
      for (int t=0;t<4;++t) bH[t]=LDF(xp,t,kt);
      #pragma unroll
      for (int mt=0;mt<4;++mt){
        short8 aH = GBF(wb+O_WPH, mt, kt);
        #pragma unroll
        for (int nt=0;nt<4;++nt)
          acc[mt][nt] = MFMA16(aH, bH[nt], acc[mt][nt], 0,0,0);
      }
    }
    #pragma unroll
    for (int mt=0;mt<4;++mt)
      #pragma unroll
      for (int nt=0;nt<4;++nt){
        short4v vh;
        #pragma unroll
        for (int r=0;r<4;++r) vh[r] = (short)f2bf(fmaxf(acc[mt][nt][r], 0.0f));
        *(short4v*)&xp[CFO(mt,nt)] = vh;
      }
    asm volatile("s_waitcnt lgkmcnt(0)" ::: "memory");
  }

  // ---- GNN layers: h^T = Ws^T@x^T + (A@(x@Wn))^T + bconv; x += relu(LN(h)) ----
  #pragma unroll 1
  for (int L=0; L<NL; ++L){
    const ushort* WsH = wb + O_WSH + L*4096;
    const ushort* WnH = wb + O_WNH + L*4096;

    // h = bconv + Ws^T(A,hi) @ x^T(B,hi) — B-frags transient per kt
    f32x4 h[4][4];
    #pragma unroll
    for (int mt=0;mt<4;++mt){
      f32x4 b4 = *(const f32x4*)&bconv[L*64 + 16*mt + hk*4];
      #pragma unroll
      for (int nt=0;nt<4;++nt) h[mt][nt] = b4;
    }
    #pragma unroll
    for (int kt=0;kt<2;++kt){
      short8 bH[4];
      #pragma unroll
      for (int t=0;t<4;++t) bH[t]=LDF(xp,t,kt);
      #pragma unroll
      for (int mt=0;mt<4;++mt){
        short8 aH = GBF(WsH, mt, kt);
        #pragma unroll
        for (int nt=0;nt<4;++nt)
          h[mt][nt] = MFMA16(aH, bH[nt], h[mt][nt], 0,0,0);
      }
    }

    // h += (A @ (x@Wn))^T, one 16-ofeat slab at a time (x-frags loaded per use)
    #pragma unroll
    for (int ft=0;ft<4;++ft){
      f32x4 y4[4];
      #pragma unroll
      for (int mt=0;mt<4;++mt) y4[mt] = (f32x4){0.f,0.f,0.f,0.f};
      #pragma unroll
      for (int kt=0;kt<2;++kt){
        short8 wH = GBF(WnH, ft, kt);
        #pragma unroll
        for (int mt=0;mt<4;++mt){
          short8 xfH = LDF(xp, mt, kt);
          y4[mt] = MFMA16(xfH, wH, y4[mt], 0,0,0);
        }
      }
      #pragma unroll
      for (int mt=0;mt<4;++mt){
        short4v vh;
        #pragma unroll
        for (int r=0;r<4;++r) vh[r] = (short)f2bf(y4[mt][r]);
        int off = c*64 + ((16*mt + 4*hk) ^ ((c&7)<<3));
        *(short4v*)&sl[off] = vh;
      }
      asm volatile("s_waitcnt lgkmcnt(0)" ::: "memory");
      #pragma unroll
      for (int kt=0;kt<2;++kt){
        int ro = c*64 + ((32*kt + 8*hk) ^ ((c&7)<<3));
        short8 saH = *(const short8*)&sl[ro];
        #pragma unroll
        for (int nt=0;nt<4;++nt){
          short8 bH = GBF(wb+O_ADJH, nt, kt);
          short8 bL = GBF(wb+O_ADJL, nt, kt);
          h[ft][nt] = MFMA16(saH, bH, h[ft][nt], 0,0,0);
          h[ft][nt] = MFMA16(saH, bL, h[ft][nt], 0,0,0);
        }
      }
    }

    // LN over feats per node + relu + residual (x_old hi from LDS, write hi)
    f32x4 g4[4], bb4[4];
    #pragma unroll
    for (int mt=0;mt<4;++mt){
      g4[mt]  = *(const f32x4*)&lng[L*64 + 16*mt + hk*4];
      bb4[mt] = *(const f32x4*)&lnb[L*64 + 16*mt + hk*4];
    }
    #pragma unroll
    for (int nt=0;nt<4;++nt){
      float sm=0.0f, sq=0.0f;
      #pragma unroll
      for (int mt=0;mt<4;++mt)
        #pragma unroll
        for (int r=0;r<4;++r){ float v=h[mt][nt][r]; sm+=v; sq+=v*v; }
      sm += __shfl_xor(sm,16,64); sm += __shfl_xor(sm,32,64);
      sq += __shfl_xor(sq,16,64); sq += __shfl_xor(sq,32,64);
      float mu  = sm*(1.0f/64.0f);
      float var = sq*(1.0f/64.0f) - mu*mu;
      float rs  = rsqrtf(var + 1e-5f);
      #pragma unroll
      for (int mt=0;mt<4;++mt){
        int off = CFO(mt,nt);
        short4v oh = *(const short4v*)&xp[off];
        short4v vh;
        #pragma unroll
        for (int r=0;r<4;++r){
          float hn = (h[mt][nt][r]-mu)*rs*g4[mt][r] + bb4[mt][r];
          float v  = bf2f((ushort)oh[r]) + fmaxf(hn, 0.0f);
          vh[r] = (short)f2bf(v);
        }
        *(short4v*)&xp[off] = vh;
      }
    }
    asm volatile("s_waitcnt lgkmcnt(0)" ::: "memory");
  }

  // ---- codons: x read from LDS (hi) ----
  {
    f32x4 wc4[4];
    #pragma unroll
    for (int mt=0;mt<4;++mt) wc4[mt] = *(const f32x4*)&Wcod[16*mt + hk*4];
    float bc = bcod[0];
    #pragma unroll
    for (int nt=0;nt<4;++nt){
      float p = 0.0f;
      #pragma unroll
      for (int mt=0;mt<4;++mt){
        short4v oh = *(const short4v*)&xp[CFO(mt,nt)];
        #pragma unroll
        for (int r=0;r<4;++r) p = fmaf(bf2f((ushort)oh[r]), wc4[mt][r], p);
      }
      p += __shfl_xor(p,16,64); p += __shfl_xor(p,32,64);
      if (hk==0) oute[16*nt + c] = sigm(p + bc);
    }
  }

  // ---- heads: scores via MFMA (A1 hi, x hi); softmax + pool (x from LDS) ----
  float sc[NH];
  {
    #pragma unroll 1
    for (int hd=0; hd<NH; ++hd){
      float m4[4];
      #pragma unroll
      for (int nt=0;nt<4;++nt) m4[nt] = (float)masks[hd*64 + 16*nt + c];

      f32x4 s2[2][4];
      #pragma unroll
      for (int mt=0;mt<2;++mt)
        #pragma unroll
        for (int nt=0;nt<4;++nt) s2[mt][nt] = (f32x4){0.f,0.f,0.f,0.f};
      const ushort* A1H = wb + O_A1H + hd*2048;
      #pragma unroll
      for (int kt=0;kt<2;++kt){
        short8 bH[4];
        #pragma unroll
        for (int t=0;t<4;++t) bH[t]=LDF(xp,t,kt);
        #pragma unroll
        for (int mt=0;mt<2;++mt){
          short8 aH = GBF(A1H, mt, kt);
          #pragma unroll
          for (int nt=0;nt<4;++nt)
            s2[mt][nt] = MFMA16(aH, bH[nt], s2[mt][nt], 0,0,0);
        }
      }
      float sp[4] = {0.f,0.f,0.f,0.f};
      #pragma unroll
      for (int mt=0;mt<2;++mt){
        f32x4 b1v = *(const f32x4*)&a1b[hd*32 + 16*mt + hk*4];
        f32x4 a2v = *(const f32x4*)&a2W[hd*32 + 16*mt + hk*4];
        #pragma unroll
        for (int nt=0;nt<4;++nt)
          #pragma unroll
          for (int r=0;r<4;++r)
            sp[nt] = fmaf(ftanh(fmaf(m4[nt], s2[mt][nt][r], b1v[r])), a2v[r], sp[nt]);
      }
      float a2bv = a2b[hd];
      float sv[4];
      #pragma unroll
      for (int nt=0;nt<4;++nt){
        float t = sp[nt];
        t += __shfl_xor(t,16,64); t += __shfl_xor(t,32,64);
        sv[nt] = t + a2bv + (1.0f - m4[nt])*(-1.0e9f);
      }
      float mx = fmaxf(fmaxf(sv[0],sv[1]), fmaxf(sv[2],sv[3]));
      #pragma unroll
      for (int d=1; d<16; d<<=1) mx = fmaxf(mx, __shfl_xor(mx,d,64));
      float ee[4], ssum=0.0f;
      #pragma unroll
      for (int nt=0;nt<4;++nt){ ee[nt] = __expf(sv[nt]-mx); ssum += ee[nt]; }
      #pragma unroll
      for (int d=1; d<16; d<<=1) ssum += __shfl_xor(ssum,d,64);
      float inv = 1.0f/ssum;
      float wgt[4];
      #pragma unroll
      for (int nt=0;nt<4;++nt) wgt[nt] = ee[nt]*inv*m4[nt];
      // pooled[feat] = sum_node wgt*x, x from LDS (hi)
      float dt = 0.0f;
      #pragma unroll
      for (int mt=0;mt<4;++mt){
        f32x4 ow = *(const f32x4*)&oW[hd*64 + 16*mt + hk*4];
        float pr[4] = {0.f,0.f,0.f,0.f};
        #pragma unroll
        for (int nt=0;nt<4;++nt){
          short4v oh = *(const short4v*)&xp[CFO(mt, nt)];
          #pragma unroll
          for (int r=0;r<4;++r)
            pr[r] = fmaf(wgt[nt], bf2f((ushort)oh[r]), pr[r]);
        }
        #pragma unroll
        for (int r=0;r<4;++r){
          float pv = pr[r];
          #pragma unroll
          for (int d=1; d<16; d<<=1) pv += __shfl_xor(pv,d,64);
          dt = fmaf(pv, ow[r], dt);
        }
      }
      dt += __shfl_xor(dt,16,64); dt += __shfl_xor(dt,32,64);
      sc[hd] = sigm(dt + ob[hd]);
    }
  }

  // ---- FiLM: lanes 0-31 idx0, 32-63 idx1 ----
  {
    int idx = lane >> 5;
    int j   = lane & 31;
    float t = fb1[idx*32 + j];
    const float* fw = fW1 + idx*SUN*32 + j;
    const float* se = sun + e*(long)SUN;
    #pragma unroll 8
    for (int k=0;k<SUN;++k) t = fmaf(se[k], fw[k*32], t);
    t = fmaxf(t, 0.0f);
    float g  = t * fW2[idx*64 + j*2 + 0];
    float be = t * fW2[idx*64 + j*2 + 1];
    #pragma unroll
    for (int d=1; d<32; d<<=1){ g += __shfl_xor(g,d,64); be += __shfl_xor(be,d,64); }
    float base = (lane < 32) ? sc[3] : sc[4];
    if (j == 0){
      g  += fb2[idx*2 + 0];
      be += fb2[idx*2 + 1];
      oute[67 + idx] = sigm(fmaf(g, base, be));
    }
  }
  if (lane == 0){
    oute[64] = sc[0];
    oute[65] = sc[1];
    oute[66] = sc[2];
  }
}

extern "C" void kernel_launch(void* const* d_in, const int* in_sizes, int n_in,
                              void* d_out, int out_size, void* d_ws, size_t ws_size,
                              hipStream_t stream){
  const float* nf     = (const float*)d_in[0];
  const float* sun    = (const float*)d_in[1];
  const int*   ei     = (const int*)d_in[2];
  const int*   masks  = (const int*)d_in[3];
  const float* Wp     = (const float*)d_in[4];
  const float* bp     = (const float*)d_in[5];
  const float* Wself  = (const float*)d_in[6];
  const float* Wneigh = (const float*)d_in[7];
  const float* bconv  = (const float*)d_in[8];
  const float* lng    = (const float*)d_in[9];
  const float* lnb    = (const float*)d_in[10];
  const float* Wcod   = (const float*)d_in[11];
  const float* bcod   = (const float*)d_in[12];
  const float* a1W    = (const float*)d_in[13];
  const float* a1b    = (const float*)d_in[14];
  const float* a2W    = (const float*)d_in[15];
  const float* a2b    = (const float*)d_in[16];
  const float* oW     = (const float*)d_in[17];
  const float* ob     = (const float*)d_in[18];
  const float* fW1    = (const float*)d_in[19];
  const float* fb1    = (const float*)d_in[20];
  const float* fW2    = (const float*)d_in[21];
  const float* fb2    = (const float*)d_in[22];

  int B = in_sizes[0] / (NN*IN_DIM);
  int E = in_sizes[2] / 2;

  ushort* wbuf = (ushort*)d_ws;

  setup_k<<<1, 256, 0, stream>>>(ei, E, Wp, Wself, Wneigh, a1W, wbuf);
  int nb = (B + 3) / 4;
  gnn_fused<<<nb, 256, 0, stream>>>(nf, sun, masks, bp, bconv, lng, lnb, Wcod, bcod,
      a1b, a2W, a2b, oW, ob, fW1, fb1, fW2, fb2, wbuf, B, (float*)d_out);
}

// Round 23
// 436.382 us; speedup vs baseline: 1.0521x; 1.0521x over previous
//
#include <hip/hip_runtime.h>

#define NN 64
#define IN_DIM 34
#define SUN 70
#define NL 3
#define NH 5

typedef __attribute__((ext_vector_type(8))) short short8;
typedef __attribute__((ext_vector_type(4))) short short4v;
typedef __attribute__((ext_vector_type(4))) float f32x4;
#define MFMA16 __builtin_amdgcn_mfma_f32_16x16x32_bf16

__device__ __forceinline__ float sigm(float x){ return 1.0f/(1.0f+__expf(-x)); }
__device__ __forceinline__ float ftanh(float x){
  x = fminf(fmaxf(x, -15.0f), 15.0f);
  float e = __expf(2.0f*x);
  return (e-1.0f)/(e+1.0f);
}
__device__ __forceinline__ ushort f2bf(float f){
  union { float f; unsigned u; } v; v.f = f;
  unsigned r = v.u + 0x7fff + ((v.u >> 16) & 1);   // RNE
  return (ushort)(r >> 16);
}
__device__ __forceinline__ float bf2f(ushort h){
  union { unsigned u; float f; } v; v.u = ((unsigned)h) << 16;
  return v.f;
}

// ws ushort offsets (weights single-bf16; adj hi/lo)
#define O_WPH 0
#define O_WSH 4096
#define O_WNH 16384
#define O_A1H 28672
#define O_ADJH 38912
#define O_ADJL 43008

// fragment-order permutation within a plane (coalesced GBF reads)
__device__ __forceinline__ int fragoff(int i){
  int e = i>>6, k = i&63;
  int t = e>>4, cc = e&15, kt = (k>>5)&1, hk = (k>>3)&3, j = k&7;
  return (((t*2+kt)*64) + (hk*16+cc))*8 + j;
}

// LDS frag read: storage [entity][k] swizzled; entity = 16t+c, k = hk*8 + kt*32
#define LDF(plane, t, kt) \
  (*(const short8*)&(plane)[(16*(t)+c)*64 + (((hk*8)+(kt)*32) ^ (((16*(t)+c)&7)<<3))])
// global wb frag read (fragment-ordered, fully coalesced)
#define GBF(base, t, kt) \
  (*(const short8*)&(base)[(((t)*2+(kt))*64 + lane)*8])
// C-frag LDS offset for (mt,nt)
#define CFO(mt, nt) ((16*(nt)+c)*64 + (((16*(mt)+hk*4)) ^ (((16*(nt)+c)&7)<<3)))

// Setup: dense normalized adjacency (hi/lo) + weights single-bf16, frag-ordered.
__global__ void setup_k(const int* __restrict__ ei, int E,
                        const float* __restrict__ Wp, const float* __restrict__ Wself,
                        const float* __restrict__ Wneigh, const float* __restrict__ a1W,
                        ushort* __restrict__ wb){
  __shared__ float A[64*64];
  __shared__ float dv[64];
  int tid = threadIdx.x;
  for (int i=tid;i<4096;i+=256) A[i]=0.0f;
  __syncthreads();
  if (tid==0){
    for (int e=0;e<E;++e) A[ei[E+e]*64 + ei[e]] += 1.0f;
  }
  __syncthreads();
  if (tid<64){
    float s=0.0f;
    for (int k=0;k<64;++k) s += A[tid*64+k];
    dv[tid] = 1.0f/fmaxf(s,1.0f);
  }
  __syncthreads();
  for (int i=tid;i<4096;i+=256){
    int d=i>>6;
    float v = A[i]*dv[d];
    ushort h=f2bf(v);
    int fo = fragoff(i);
    wb[O_ADJH+fo]=h; wb[O_ADJL+fo]=f2bf(v-bf2f(h));
  }
  for (int i = tid; i < 4096; i += 256){
    int n = i>>6, k = i&63;
    float w = (k < IN_DIM) ? Wp[k*64 + n] : 0.0f;
    wb[O_WPH+fragoff(i)] = f2bf(w);
  }
  for (int i = tid; i < 3*4096; i += 256){
    int L = i>>12, r = i&4095, n = r>>6, k = r&63;
    int fo = L*4096 + fragoff(r);
    wb[O_WSH+fo] = f2bf(Wself[L*4096 + k*64 + n]);
    wb[O_WNH+fo] = f2bf(Wneigh[L*4096 + k*64 + n]);
  }
  for (int i = tid; i < 5*2048; i += 256){
    int hd = i>>11, r = i&2047, cc = r>>6, k = r&63;
    wb[O_A1H + hd*2048 + fragoff(r)] = f2bf(a1W[hd*2048 + k*32 + cc]);
  }
}

__global__ __launch_bounds__(256, 2) void gnn_fused(
    const float* __restrict__ nf, const float* __restrict__ sun,
    const int* __restrict__ masks,
    const float* __restrict__ bp, const float* __restrict__ bconv,
    const float* __restrict__ lng, const float* __restrict__ lnb,
    const float* __restrict__ Wcod, const float* __restrict__ bcod,
    const float* __restrict__ a1b, const float* __restrict__ a2W,
    const float* __restrict__ a2b,
    const float* __restrict__ oW, const float* __restrict__ ob,
    const float* __restrict__ fW1, const float* __restrict__ fb1,
    const float* __restrict__ fW2, const float* __restrict__ fb2,
    const ushort* __restrict__ wb, int B,
    float* __restrict__ out)
{
  __shared__ ushort s_x[4][4096];    // per-wave x: bf16 hi only, swizzled [node][feat]
  __shared__ ushort s_slab[4][1024]; // per-wave yT slab, single bf16

  const int tid  = threadIdx.x;
  const int lane = tid & 63;
  const int wv   = __builtin_amdgcn_readfirstlane(tid >> 6);
  const int c    = lane & 15;
  const int hk   = lane >> 4;
  const long e   = (long)blockIdx.x*4 + wv;
  if (e >= B) return;

  ushort* xp = s_x[wv];
  ushort* sl = s_slab[wv];
  float*  oute = out + e*69;

  // ---- stage nf into xp (hi only), coalesced float2 loads ----
  {
    const float* nfe = nf + e*(long)(NN*IN_DIM);
    for (int p = lane; p < 1088; p += 64){           // 17 iters, fully coalesced
      int n = p/17, k = 2*(p - n*17);
      float2 v = *(const float2*)&nfe[n*IN_DIM + k];
      int off = n*64 + (k ^ ((n&7)<<3));
      *(unsigned*)&xp[off] = (unsigned)f2bf(v.x) | ((unsigned)f2bf(v.y)<<16);
    }
    int n = lane, key = (n&7)<<3;
    int off34 = n*64 + (34 ^ key);
    *(unsigned*)&xp[off34] = 0;
    #pragma unroll
    for (int k4 = 9; k4 < 16; ++k4){
      int off = n*64 + ((k4*4) ^ key);
      *(short4v*)&xp[off] = (short4v){0,0,0,0};
    }
    asm volatile("s_waitcnt lgkmcnt(0)" ::: "memory");
  }

  // ---- proj^T = Wp^T(A,hi) @ nf^T(B,hi): relu -> LDS (hi) ----
  {
    f32x4 acc[4][4];
    #pragma unroll
    for (int mt=0;mt<4;++mt){
      f32x4 b4 = *(const f32x4*)&bp[16*mt + hk*4];
      #pragma unroll
      for (int nt=0;nt<4;++nt) acc[mt][nt] = b4;
    }
    #pragma unroll
    for (int kt=0; kt<2; ++kt){
      short8 bH[4];
      #pragma unroll
      for (int t=0;t<4;++t) bH[t]=LDF(xp,t,kt);
      #pragma unroll
      for (int mt=0;mt<4;++mt){
        short8 aH = GBF(wb+O_WPH, mt, kt);
        #pragma unroll
        for (int nt=0;nt<4;++nt)
          acc[mt][nt] = MFMA16(aH, bH[nt], acc[mt][nt], 0,0,0);
      }
    }
    #pragma unroll
    for (int mt=0;mt<4;++mt)
      #pragma unroll
      for (int nt=0;nt<4;++nt){
        short4v vh;
        #pragma unroll
        for (int r=0;r<4;++r) vh[r] = (short)f2bf(fmaxf(acc[mt][nt][r], 0.0f));
        *(short4v*)&xp[CFO(mt,nt)] = vh;
      }
    asm volatile("s_waitcnt lgkmcnt(0)" ::: "memory");
  }

  // ---- GNN layers: h^T = Ws^T@x^T + (A@(x@Wn))^T + bconv; x += relu(LN(h)) ----
  #pragma unroll 1
  for (int L=0; L<NL; ++L){
    const ushort* WsH = wb + O_WSH + L*4096;
    const ushort* WnH = wb + O_WNH + L*4096;

    // h = bconv + Ws^T(A,hi) @ x^T(B,hi) — B-frags transient per kt
    f32x4 h[4][4];
    #pragma unroll
    for (int mt=0;mt<4;++mt){
      f32x4 b4 = *(const f32x4*)&bconv[L*64 + 16*mt + hk*4];
      #pragma unroll
      for (int nt=0;nt<4;++nt) h[mt][nt] = b4;
    }
    #pragma unroll
    for (int kt=0;kt<2;++kt){
      short8 bH[4];
      #pragma unroll
      for (int t=0;t<4;++t) bH[t]=LDF(xp,t,kt);
      #pragma unroll
      for (int mt=0;mt<4;++mt){
        short8 aH = GBF(WsH, mt, kt);
        #pragma unroll
        for (int nt=0;nt<4;++nt)
          h[mt][nt] = MFMA16(aH, bH[nt], h[mt][nt], 0,0,0);
      }
    }

    // h += (A @ (x@Wn))^T, one 16-ofeat slab at a time (x-frags loaded per use)
    #pragma unroll
    for (int ft=0;ft<4;++ft){
      f32x4 y4[4];
      #pragma unroll
      for (int mt=0;mt<4;++mt) y4[mt] = (f32x4){0.f,0.f,0.f,0.f};
      #pragma unroll
      for (int kt=0;kt<2;++kt){
        short8 wH = GBF(WnH, ft, kt);
        #pragma unroll
        for (int mt=0;mt<4;++mt){
          short8 xfH = LDF(xp, mt, kt);
          y4[mt] = MFMA16(xfH, wH, y4[mt], 0,0,0);
        }
      }
      #pragma unroll
      for (int mt=0;mt<4;++mt){
        short4v vh;
        #pragma unroll
        for (int r=0;r<4;++r) vh[r] = (short)f2bf(y4[mt][r]);
        int off = c*64 + ((16*mt + 4*hk) ^ ((c&7)<<3));
        *(short4v*)&sl[off] = vh;
      }
      asm volatile("s_waitcnt lgkmcnt(0)" ::: "memory");
      #pragma unroll
      for (int kt=0;kt<2;++kt){
        int ro = c*64 + ((32*kt + 8*hk) ^ ((c&7)<<3));
        short8 saH = *(const short8*)&sl[ro];
        #pragma unroll
        for (int nt=0;nt<4;++nt){
          short8 bH = GBF(wb+O_ADJH, nt, kt);
          short8 bL = GBF(wb+O_ADJL, nt, kt);
          h[ft][nt] = MFMA16(saH, bH, h[ft][nt], 0,0,0);
          h[ft][nt] = MFMA16(saH, bL, h[ft][nt], 0,0,0);
        }
      }
    }

    // LN over feats per node + relu + residual (x_old hi from LDS, write hi)
    f32x4 g4[4], bb4[4];
    #pragma unroll
    for (int mt=0;mt<4;++mt){
      g4[mt]  = *(const f32x4*)&lng[L*64 + 16*mt + hk*4];
      bb4[mt] = *(const f32x4*)&lnb[L*64 + 16*mt + hk*4];
    }
    #pragma unroll
    for (int nt=0;nt<4;++nt){
      float sm=0.0f, sq=0.0f;
      #pragma unroll
      for (int mt=0;mt<4;++mt)
        #pragma unroll
        for (int r=0;r<4;++r){ float v=h[mt][nt][r]; sm+=v; sq+=v*v; }
      sm += __shfl_xor(sm,16,64); sm += __shfl_xor(sm,32,64);
      sq += __shfl_xor(sq,16,64); sq += __shfl_xor(sq,32,64);
      float mu  = sm*(1.0f/64.0f);
      float var = sq*(1.0f/64.0f) - mu*mu;
      float rs  = rsqrtf(var + 1e-5f);
      #pragma unroll
      for (int mt=0;mt<4;++mt){
        int off = CFO(mt,nt);
        short4v oh = *(const short4v*)&xp[off];
        short4v vh;
        #pragma unroll
        for (int r=0;r<4;++r){
          float hn = (h[mt][nt][r]-mu)*rs*g4[mt][r] + bb4[mt][r];
          float v  = bf2f((ushort)oh[r]) + fmaxf(hn, 0.0f);
          vh[r] = (short)f2bf(v);
        }
        *(short4v*)&xp[off] = vh;
      }
    }
    asm volatile("s_waitcnt lgkmcnt(0)" ::: "memory");
  }

  // ---- load final x into registers: xr[mt][nt][r] (h dead; room at 2 waves) ----
  float xr[4][4][4];
  #pragma unroll
  for (int mt=0;mt<4;++mt)
    #pragma unroll
    for (int nt=0;nt<4;++nt){
      short4v oh = *(const short4v*)&xp[CFO(mt,nt)];
      #pragma unroll
      for (int r=0;r<4;++r) xr[mt][nt][r] = bf2f((ushort)oh[r]);
    }

  // ---- codons (from registers) ----
  {
    f32x4 wc4[4];
    #pragma unroll
    for (int mt=0;mt<4;++mt) wc4[mt] = *(const f32x4*)&Wcod[16*mt + hk*4];
    float bc = bcod[0];
    #pragma unroll
    for (int nt=0;nt<4;++nt){
      float p = 0.0f;
      #pragma unroll
      for (int mt=0;mt<4;++mt)
        #pragma unroll
        for (int r=0;r<4;++r) p = fmaf(xr[mt][nt][r], wc4[mt][r], p);
      p += __shfl_xor(p,16,64); p += __shfl_xor(p,32,64);
      if (hk==0) oute[16*nt + c] = sigm(p + bc);
    }
  }

  // ---- heads: scores via MFMA (A1 hi, x hi); softmax + pool (from registers) ----
  float sc[NH];
  {
    #pragma unroll 1
    for (int hd=0; hd<NH; ++hd){
      float m4[4];
      #pragma unroll
      for (int nt=0;nt<4;++nt) m4[nt] = (float)masks[hd*64 + 16*nt + c];

      f32x4 s2[2][4];
      #pragma unroll
      for (int mt=0;mt<2;++mt)
        #pragma unroll
        for (int nt=0;nt<4;++nt) s2[mt][nt] = (f32x4){0.f,0.f,0.f,0.f};
      const ushort* A1H = wb + O_A1H + hd*2048;
      #pragma unroll
      for (int kt=0;kt<2;++kt){
        short8 bH[4];
        #pragma unroll
        for (int t=0;t<4;++t) bH[t]=LDF(xp,t,kt);
        #pragma unroll
        for (int mt=0;mt<2;++mt){
          short8 aH = GBF(A1H, mt, kt);
          #pragma unroll
          for (int nt=0;nt<4;++nt)
            s2[mt][nt] = MFMA16(aH, bH[nt], s2[mt][nt], 0,0,0);
        }
      }
      float sp[4] = {0.f,0.f,0.f,0.f};
      #pragma unroll
      for (int mt=0;mt<2;++mt){
        f32x4 b1v = *(const f32x4*)&a1b[hd*32 + 16*mt + hk*4];
        f32x4 a2v = *(const f32x4*)&a2W[hd*32 + 16*mt + hk*4];
        #pragma unroll
        for (int nt=0;nt<4;++nt)
          #pragma unroll
          for (int r=0;r<4;++r)
            sp[nt] = fmaf(ftanh(fmaf(m4[nt], s2[mt][nt][r], b1v[r])), a2v[r], sp[nt]);
      }
      float a2bv = a2b[hd];
      float sv[4];
      #pragma unroll
      for (int nt=0;nt<4;++nt){
        float t = sp[nt];
        t += __shfl_xor(t,16,64); t += __shfl_xor(t,32,64);
        sv[nt] = t + a2bv + (1.0f - m4[nt])*(-1.0e9f);
      }
      float mx = fmaxf(fmaxf(sv[0],sv[1]), fmaxf(sv[2],sv[3]));
      #pragma unroll
      for (int d=1; d<16; d<<=1) mx = fmaxf(mx, __shfl_xor(mx,d,64));
      float ee[4], ssum=0.0f;
      #pragma unroll
      for (int nt=0;nt<4;++nt){ ee[nt] = __expf(sv[nt]-mx); ssum += ee[nt]; }
      #pragma unroll
      for (int d=1; d<16; d<<=1) ssum += __shfl_xor(ssum,d,64);
      float inv = 1.0f/ssum;
      float wgt[4];
      #pragma unroll
      for (int nt=0;nt<4;++nt) wgt[nt] = ee[nt]*inv*m4[nt];
      float dt = 0.0f;
      #pragma unroll
      for (int mt=0;mt<4;++mt){
        f32x4 ow = *(const f32x4*)&oW[hd*64 + 16*mt + hk*4];
        #pragma unroll
        for (int r=0;r<4;++r){
          float pv = wgt[0]*xr[mt][0][r] + wgt[1]*xr[mt][1][r]
                   + wgt[2]*xr[mt][2][r] + wgt[3]*xr[mt][3][r];
          #pragma unroll
          for (int d=1; d<16; d<<=1) pv += __shfl_xor(pv,d,64);
          dt = fmaf(pv, ow[r], dt);
        }
      }
      dt += __shfl_xor(dt,16,64); dt += __shfl_xor(dt,32,64);
      sc[hd] = sigm(dt + ob[hd]);
    }
  }

  // ---- FiLM: lanes 0-31 idx0, 32-63 idx1 ----
  {
    int idx = lane >> 5;
    int j   = lane & 31;
    float t = fb1[idx*32 + j];
    const float* fw = fW1 + idx*SUN*32 + j;
    const float* se = sun + e*(long)SUN;
    #pragma unroll 8
    for (int k=0;k<SUN;++k) t = fmaf(se[k], fw[k*32], t);
    t = fmaxf(t, 0.0f);
    float g  = t * fW2[idx*64 + j*2 + 0];
    float be = t * fW2[idx*64 + j*2 + 1];
    #pragma unroll
    for (int d=1; d<32; d<<=1){ g += __shfl_xor(g,d,64); be += __shfl_xor(be,d,64); }
    float base = (lane < 32) ? sc[3] : sc[4];
    if (j == 0){
      g  += fb2[idx*2 + 0];
      be += fb2[idx*2 + 1];
      oute[67 + idx] = sigm(fmaf(g, base, be));
    }
  }
  if (lane == 0){
    oute[64] = sc[0];
    oute[65] = sc[1];
    oute[66] = sc[2];
  }
}

extern "C" void kernel_launch(void* const* d_in, const int* in_sizes, int n_in,
                              void* d_out, int out_size, void* d_ws, size_t ws_size,
                              hipStream_t stream){
  const float* nf     = (const float*)d_in[0];
  const float* sun    = (const float*)d_in[1];
  const int*   ei     = (const int*)d_in[2];
  const int*   masks  = (const int*)d_in[3];
  const float* Wp     = (const float*)d_in[4];
  const float* bp     = (const float*)d_in[5];
  const float* Wself  = (const float*)d_in[6];
  const float* Wneigh = (const float*)d_in[7];
  const float* bconv  = (const float*)d_in[8];
  const float* lng    = (const float*)d_in[9];
  const float* lnb    = (const float*)d_in[10];
  const float* Wcod   = (const float*)d_in[11];
  const float* bcod   = (const float*)d_in[12];
  const float* a1W    = (const float*)d_in[13];
  const float* a1b    = (const float*)d_in[14];
  const float* a2W    = (const float*)d_in[15];
  const float* a2b    = (const float*)d_in[16];
  const float* oW     = (const float*)d_in[17];
  const float* ob     = (const float*)d_in[18];
  const float* fW1    = (const float*)d_in[19];
  const float* fb1    = (const float*)d_in[20];
  const float* fW2    = (const float*)d_in[21];
  const float* fb2    = (const float*)d_in[22];

  int B = in_sizes[0] / (NN*IN_DIM);
  int E = in_sizes[2] / 2;

  ushort* wbuf = (ushort*)d_ws;

  setup_k<<<1, 256, 0, stream>>>(ei, E, Wp, Wself, Wneigh, a1W, wbuf);
  int nb = (B + 3) / 4;
  gnn_fused<<<nb, 256, 0, stream>>>(nf, sun, masks, bp, bconv, lng, lnb, Wcod, bcod,
      a1b, a2W, a2b, oW, ob, fW1, fb1, fW2, fb2, wbuf, B, (float*)d_out);
}